// Round 7
// baseline (122.556 us; speedup 1.0000x reference)
//
#include <hip/hip_runtime.h>

#define HIDDEN   1024
#define NEXP     8
#define NTOK     32768           // 4 * 8192
#define TOK_PER_WAVE 8
#define WAVES_PER_BLOCK 4
#define NBLOCKS  (NTOK / (TOK_PER_WAVE * WAVES_PER_BLOCK))   // 1024

// Dual-token 64-lane reduction: both tokens' shuffle chains interleaved
// stage-by-stage (ILP 2 on the DS pipe). Per-token operation sequence is
// bitwise identical to the proven single-token split_reduce8 (rounds 1-5):
// same shuffles, same adds, same order — only cross-token scheduling differs.
// Returns full dot for expert (lane&7) in every lane, for both tokens.
__device__ __forceinline__ void split_reduce8x2(const float (&A)[8], const float (&B)[8],
                                                int lane, float& rA, float& rB) {
    float a4A[4], a4B[4];
    {
        const bool hi = (lane & 4) != 0;
        #pragma unroll
        for (int j = 0; j < 4; ++j) {
            float sA = hi ? A[j] : A[j + 4];
            float sB = hi ? B[j] : B[j + 4];
            float vA = __shfl_xor(sA, 4, 64);
            float vB = __shfl_xor(sB, 4, 64);
            a4A[j] = (hi ? A[j + 4] : A[j]) + vA;
            a4B[j] = (hi ? B[j + 4] : B[j]) + vB;
        }
    }
    float a2A[2], a2B[2];
    {
        const bool hi = (lane & 2) != 0;
        #pragma unroll
        for (int j = 0; j < 2; ++j) {
            float sA = hi ? a4A[j] : a4A[j + 2];
            float sB = hi ? a4B[j] : a4B[j + 2];
            float vA = __shfl_xor(sA, 2, 64);
            float vB = __shfl_xor(sB, 2, 64);
            a2A[j] = (hi ? a4A[j + 2] : a4A[j]) + vA;
            a2B[j] = (hi ? a4B[j + 2] : a4B[j]) + vB;
        }
    }
    float a1A, a1B;
    {
        const bool hi = (lane & 1) != 0;
        float sA = hi ? a2A[0] : a2A[1];
        float sB = hi ? a2B[0] : a2B[1];
        float vA = __shfl_xor(sA, 1, 64);
        float vB = __shfl_xor(sB, 1, 64);
        a1A = (hi ? a2A[1] : a2A[0]) + vA;
        a1B = (hi ? a2B[1] : a2B[0]) + vB;
    }
    {
        float vA = __shfl_xor(a1A, 8, 64);
        float vB = __shfl_xor(a1B, 8, 64);
        a1A += vA; a1B += vB;
        vA = __shfl_xor(a1A, 16, 64);
        vB = __shfl_xor(a1B, 16, 64);
        a1A += vA; a1B += vB;
        vA = __shfl_xor(a1A, 32, 64);
        vB = __shfl_xor(a1B, 32, 64);
        a1A += vA; a1B += vB;
    }
    rA = a1A; rB = a1B;
}

// Per-lane-group softmax+top2 (unchanged from rounds 2-5, proven).
__device__ __forceinline__ void softmax_top2_lane(float selv, int lane,
                                                  float& w1, float& w2,
                                                  int& i1, int& i2, float& myp) {
    const int gbase = lane & 56;
    float l[8];
    #pragma unroll
    for (int e = 0; e < 8; ++e) l[e] = __shfl(selv, gbase + e, 64);
    float m = l[0];
    #pragma unroll
    for (int e = 1; e < 8; ++e) m = fmaxf(m, l[e]);
    float p[8];
    float s = 0.f;
    #pragma unroll
    for (int e = 0; e < 8; ++e) { p[e] = __expf(l[e] - m); s += p[e]; }
    const float inv = 1.f / s;

    i1 = 0; float v1 = p[0];
    #pragma unroll
    for (int e = 1; e < 8; ++e) { if (p[e] > v1) { v1 = p[e]; i1 = e; } }
    i2 = -1; float v2 = -1.f;
    #pragma unroll
    for (int e = 0; e < 8; ++e) { if (e != i1 && p[e] > v2) { v2 = p[e]; i2 = e; } }

    const float wsum = v1 + v2;
    w1 = v1 / wsum;
    w2 = v2 / wsum;
    myp = p[lane & 7] * inv;
}

__device__ __forceinline__ void load_pair(const float4* __restrict__ h4,
                                          size_t tok, int lane,
                                          float4 (&h0)[4], float4 (&h1)[4]) {
    const size_t base = tok * 256;   // 256 float4 per row
    #pragma unroll
    for (int j = 0; j < 4; ++j) h0[j] = h4[base + j * 64 + lane];
    #pragma unroll
    for (int j = 0; j < 4; ++j) h1[j] = h4[base + 256 + j * 64 + lane];
}

__device__ __forceinline__ void process_pair(const float4 (&h0)[4], const float4 (&h1)[4],
                                             const float4 (&Wf)[8][4],
                                             int lane, int t0,
                                             float* __restrict__ out_w,
                                             float* __restrict__ out_sel,
                                             float& ps_acc, unsigned* s_cnt) {
    float acc0[8], acc1[8];
    #pragma unroll
    for (int e = 0; e < 8; ++e) {
        float a = 0.f, c = 0.f;
        #pragma unroll
        for (int j = 0; j < 4; ++j) {
            a = fmaf(h0[j].x, Wf[e][j].x, a);
            a = fmaf(h0[j].y, Wf[e][j].y, a);
            a = fmaf(h0[j].z, Wf[e][j].z, a);
            a = fmaf(h0[j].w, Wf[e][j].w, a);
            c = fmaf(h1[j].x, Wf[e][j].x, c);
            c = fmaf(h1[j].y, Wf[e][j].y, c);
            c = fmaf(h1[j].z, Wf[e][j].z, c);
            c = fmaf(h1[j].w, Wf[e][j].w, c);
        }
        acc0[e] = a; acc1[e] = c;
    }

    float r0, r1;
    split_reduce8x2(acc0, acc1, lane, r0, r1);

    const int tokSel = (lane >> 3) & 1;      // 8-lane groups alternate tokens
    const float selv = tokSel ? r1 : r0;

    float w1, w2, myp; int i1, i2;
    softmax_top2_lane(selv, lane, w1, w2, i1, i2, myp);

    // lanes 0-15 own aux prob accumulation (expert lane&7, token lane>>3)
    ps_acc += myp;

    // expert-count: lanes 0,1 (token0 i1,i2) and 8,9 (token1 i1,i2)
    if ((lane & 54) == 0)
        atomicAdd(&s_cnt[(lane & 1) ? i2 : i1], 1u);

    // writes: lane 0 -> token t0, lane 8 -> token t0+1
    if ((lane & 55) == 0) {
        const int t = t0 + tokSel;
        ((float2*)out_w)[t]   = make_float2(w1, w2);
        ((float2*)out_sel)[t] = make_float2((float)i1, (float)i2);
    }
}

// launch_bounds: max-threads only. Round 3 proved a min-waves arg of 4
// forces a 64-VGPR target -> 122 MB spill traffic, 3.5x regression.
__global__ __launch_bounds__(256)
void moe_router_kernel(const float* __restrict__ h, const float* __restrict__ wg,
                       float* __restrict__ out_w, float* __restrict__ out_sel,
                       float* __restrict__ aux,
                       float* __restrict__ g_ps, unsigned* __restrict__ g_cnt,
                       unsigned* __restrict__ g_ctr) {
    __shared__ float    s_ps[8];
    __shared__ unsigned s_cnt[8];
    const int tid  = threadIdx.x;
    const int lane = tid & 63;
    const int widx = tid >> 6;

    if (tid < 8) { s_ps[tid] = 0.f; s_cnt[tid] = 0u; }
    __syncthreads();

    const float4* wg4 = (const float4*)wg;
    float4 Wf[8][4];
    #pragma unroll
    for (int e = 0; e < 8; ++e)
        #pragma unroll
        for (int j = 0; j < 4; ++j)
            Wf[e][j] = wg4[e * 256 + j * 64 + lane];

    #pragma unroll
    for (int e = 0; e < 8; ++e)
        #pragma unroll
        for (int j = 0; j < 4; ++j)
            asm volatile("" : "+v"(Wf[e][j].x), "+v"(Wf[e][j].y),
                              "+v"(Wf[e][j].z), "+v"(Wf[e][j].w));

    const int gw      = blockIdx.x * WAVES_PER_BLOCK + widx;
    const int tokBase = gw * TOK_PER_WAVE;
    const float4* h4  = (const float4*)h;
    float ps_acc = 0.f;

    float4 hA0[4], hA1[4], hB0[4], hB1[4];
    load_pair(h4, (size_t)tokBase, lane, hA0, hA1);

    #pragma unroll
    for (int bb = 0; bb < TOK_PER_WAVE / 4; ++bb) {
        const int tA = tokBase + 4 * bb;
        const int tB = tA + 2;
        load_pair(h4, (size_t)tB, lane, hB0, hB1);                 // prefetch B
        process_pair(hA0, hA1, Wf, lane, tA, out_w, out_sel, ps_acc, s_cnt);
        if (bb < TOK_PER_WAVE / 4 - 1)
            load_pair(h4, (size_t)(tA + 4), lane, hA0, hA1);       // prefetch next A
        process_pair(hB0, hB1, Wf, lane, tB, out_w, out_sel, ps_acc, s_cnt);
    }

    if (lane < 16) atomicAdd(&s_ps[lane & 7], ps_acc);
    __syncthreads();

    // Accumulate into device-scope globals (zeroed by the 80B memsetAsync).
    if (tid < 8) {
        atomicAdd(&g_ps[tid],  s_ps[tid]);
        atomicAdd(&g_cnt[tid], s_cnt[tid]);
    }

    // Last-block finalize: device-scope ticket; the block that sees
    // NBLOCKS-1 knows every other block's atomics have completed
    // (threadfence orders our adds before our ticket bump; atomics are
    // coherent, so reading back via atomicAdd(p,0) avoids any stale-cache
    // path — no cooperative launch needed).
    __threadfence();
    __shared__ unsigned s_old;
    if (tid == 0) s_old = atomicAdd(g_ctr, 1u);
    __syncthreads();
    if (s_old == NBLOCKS - 1) {
        __shared__ float f_ps[8], f_cnt[8];
        if (tid < 8) {
            f_ps[tid]  = atomicAdd(&g_ps[tid], 0.0f);
            f_cnt[tid] = (float)atomicAdd(&g_cnt[tid], 0u);
        }
        __syncthreads();
        if (tid == 0) {
            const float invT = 1.0f / (float)NTOK;
            float a = 0.f;
            #pragma unroll
            for (int e = 0; e < 8; ++e)
                a += (f_cnt[e] * invT) * (f_ps[e] * invT);
            *aux = (float)NEXP * a;
        }
    }
}

extern "C" void kernel_launch(void* const* d_in, const int* in_sizes, int n_in,
                              void* d_out, int out_size, void* d_ws, size_t ws_size,
                              hipStream_t stream) {
    const float* h  = (const float*)d_in[0];   // [4, 8192, 1024] f32
    const float* wg = (const float*)d_in[1];   // [8, 1024] f32

    float* out_w   = (float*)d_out;            // [4,8192,2,1] -> 65536
    float* out_sel = out_w + 65536;            // [4,8192,2]   -> 65536 (as float)
    float* aux     = out_w + 131072;           // scalar

    float*    g_ps  = (float*)d_ws;                      // 8 floats
    unsigned* g_cnt = (unsigned*)((float*)d_ws + 8);     // 8 uints
    unsigned* g_ctr = g_cnt + 8;                         // ticket counter

    hipMemsetAsync(d_ws, 0, 80, stream);
    moe_router_kernel<<<NBLOCKS, 256, 0, stream>>>(h, wg, out_w, out_sel, aux,
                                                   g_ps, g_cnt, g_ctr);
}

// Round 8
// 42.615 us; speedup vs baseline: 2.8759x; 2.8759x over previous
//
#include <hip/hip_runtime.h>

#define HIDDEN   1024
#define NEXP     8
#define NTOK     32768           // 4 * 8192
#define TOK_PER_WAVE 8
#define WAVES_PER_BLOCK 4
#define NBLOCKS  (NTOK / (TOK_PER_WAVE * WAVES_PER_BLOCK))   // 1024
#define NBANK    32

// Dual-token 64-lane reduction: both tokens' shuffle chains interleaved
// stage-by-stage (ILP 2 on the DS pipe). Per-token operation sequence is
// bitwise identical to the proven single-token split_reduce8 (rounds 1-5).
__device__ __forceinline__ void split_reduce8x2(const float (&A)[8], const float (&B)[8],
                                                int lane, float& rA, float& rB) {
    float a4A[4], a4B[4];
    {
        const bool hi = (lane & 4) != 0;
        #pragma unroll
        for (int j = 0; j < 4; ++j) {
            float sA = hi ? A[j] : A[j + 4];
            float sB = hi ? B[j] : B[j + 4];
            float vA = __shfl_xor(sA, 4, 64);
            float vB = __shfl_xor(sB, 4, 64);
            a4A[j] = (hi ? A[j + 4] : A[j]) + vA;
            a4B[j] = (hi ? B[j + 4] : B[j]) + vB;
        }
    }
    float a2A[2], a2B[2];
    {
        const bool hi = (lane & 2) != 0;
        #pragma unroll
        for (int j = 0; j < 2; ++j) {
            float sA = hi ? a4A[j] : a4A[j + 2];
            float sB = hi ? a4B[j] : a4B[j + 2];
            float vA = __shfl_xor(sA, 2, 64);
            float vB = __shfl_xor(sB, 2, 64);
            a2A[j] = (hi ? a4A[j + 2] : a4A[j]) + vA;
            a2B[j] = (hi ? a4B[j + 2] : a4B[j]) + vB;
        }
    }
    float a1A, a1B;
    {
        const bool hi = (lane & 1) != 0;
        float sA = hi ? a2A[0] : a2A[1];
        float sB = hi ? a2B[0] : a2B[1];
        float vA = __shfl_xor(sA, 1, 64);
        float vB = __shfl_xor(sB, 1, 64);
        a1A = (hi ? a2A[1] : a2A[0]) + vA;
        a1B = (hi ? a2B[1] : a2B[0]) + vB;
    }
    {
        float vA = __shfl_xor(a1A, 8, 64);
        float vB = __shfl_xor(a1B, 8, 64);
        a1A += vA; a1B += vB;
        vA = __shfl_xor(a1A, 16, 64);
        vB = __shfl_xor(a1B, 16, 64);
        a1A += vA; a1B += vB;
        vA = __shfl_xor(a1A, 32, 64);
        vB = __shfl_xor(a1B, 32, 64);
        a1A += vA; a1B += vB;
    }
    rA = a1A; rB = a1B;
}

// Per-lane-group softmax+top2 (unchanged from rounds 2-5, proven).
__device__ __forceinline__ void softmax_top2_lane(float selv, int lane,
                                                  float& w1, float& w2,
                                                  int& i1, int& i2, float& myp) {
    const int gbase = lane & 56;
    float l[8];
    #pragma unroll
    for (int e = 0; e < 8; ++e) l[e] = __shfl(selv, gbase + e, 64);
    float m = l[0];
    #pragma unroll
    for (int e = 1; e < 8; ++e) m = fmaxf(m, l[e]);
    float p[8];
    float s = 0.f;
    #pragma unroll
    for (int e = 0; e < 8; ++e) { p[e] = __expf(l[e] - m); s += p[e]; }
    const float inv = 1.f / s;

    i1 = 0; float v1 = p[0];
    #pragma unroll
    for (int e = 1; e < 8; ++e) { if (p[e] > v1) { v1 = p[e]; i1 = e; } }
    i2 = -1; float v2 = -1.f;
    #pragma unroll
    for (int e = 0; e < 8; ++e) { if (e != i1 && p[e] > v2) { v2 = p[e]; i2 = e; } }

    const float wsum = v1 + v2;
    w1 = v1 / wsum;
    w2 = v2 / wsum;
    myp = p[lane & 7] * inv;
}

__device__ __forceinline__ void load_pair(const float4* __restrict__ h4,
                                          size_t tok, int lane,
                                          float4 (&h0)[4], float4 (&h1)[4]) {
    const size_t base = tok * 256;   // 256 float4 per row
    #pragma unroll
    for (int j = 0; j < 4; ++j) h0[j] = h4[base + j * 64 + lane];
    #pragma unroll
    for (int j = 0; j < 4; ++j) h1[j] = h4[base + 256 + j * 64 + lane];
}

__device__ __forceinline__ void process_pair(const float4 (&h0)[4], const float4 (&h1)[4],
                                             const float4 (&Wf)[8][4],
                                             int lane, int t0,
                                             float* __restrict__ out_w,
                                             float* __restrict__ out_sel,
                                             float& ps_acc, unsigned* s_cnt) {
    float acc0[8], acc1[8];
    #pragma unroll
    for (int e = 0; e < 8; ++e) {
        float a = 0.f, c = 0.f;
        #pragma unroll
        for (int j = 0; j < 4; ++j) {
            a = fmaf(h0[j].x, Wf[e][j].x, a);
            a = fmaf(h0[j].y, Wf[e][j].y, a);
            a = fmaf(h0[j].z, Wf[e][j].z, a);
            a = fmaf(h0[j].w, Wf[e][j].w, a);
            c = fmaf(h1[j].x, Wf[e][j].x, c);
            c = fmaf(h1[j].y, Wf[e][j].y, c);
            c = fmaf(h1[j].z, Wf[e][j].z, c);
            c = fmaf(h1[j].w, Wf[e][j].w, c);
        }
        acc0[e] = a; acc1[e] = c;
    }

    float r0, r1;
    split_reduce8x2(acc0, acc1, lane, r0, r1);

    const int tokSel = (lane >> 3) & 1;      // 8-lane groups alternate tokens
    const float selv = tokSel ? r1 : r0;

    float w1, w2, myp; int i1, i2;
    softmax_top2_lane(selv, lane, w1, w2, i1, i2, myp);

    // lanes 0-15 own aux prob accumulation (expert lane&7, token lane>>3)
    ps_acc += myp;

    // expert-count: lanes 0,1 (token0 i1,i2) and 8,9 (token1 i1,i2)
    if ((lane & 54) == 0)
        atomicAdd(&s_cnt[(lane & 1) ? i2 : i1], 1u);

    // writes: lane 0 -> token t0, lane 8 -> token t0+1
    if ((lane & 55) == 0) {
        const int t = t0 + tokSel;
        ((float2*)out_w)[t]   = make_float2(w1, w2);
        ((float2*)out_sel)[t] = make_float2((float)i1, (float)i2);
    }
}

// launch_bounds: max-threads only. Round 3 proved a min-waves arg of 4
// forces a 64-VGPR target -> 122 MB spill traffic, 3.5x regression.
// Round 7 proved: NO per-block __threadfence, NO same-address atomic
// accumulation (1024 adds/address = ~160 us serialization). Banked 32-way
// accumulators + __syncthreads-drained ticket instead.
__global__ __launch_bounds__(256)
void moe_router_kernel(const float* __restrict__ h, const float* __restrict__ wg,
                       float* __restrict__ out_w, float* __restrict__ out_sel,
                       float* __restrict__ aux,
                       float* __restrict__ g_bank,       // [NBANK][16], zeroed
                       unsigned* __restrict__ g_ctr) {   // ticket, zeroed
    __shared__ float    s_ps[8];
    __shared__ unsigned s_cnt[8];
    const int tid  = threadIdx.x;
    const int lane = tid & 63;
    const int widx = tid >> 6;

    if (tid < 8) { s_ps[tid] = 0.f; s_cnt[tid] = 0u; }
    __syncthreads();

    const float4* wg4 = (const float4*)wg;
    float4 Wf[8][4];
    #pragma unroll
    for (int e = 0; e < 8; ++e)
        #pragma unroll
        for (int j = 0; j < 4; ++j)
            Wf[e][j] = wg4[e * 256 + j * 64 + lane];

    #pragma unroll
    for (int e = 0; e < 8; ++e)
        #pragma unroll
        for (int j = 0; j < 4; ++j)
            asm volatile("" : "+v"(Wf[e][j].x), "+v"(Wf[e][j].y),
                              "+v"(Wf[e][j].z), "+v"(Wf[e][j].w));

    const int gw      = blockIdx.x * WAVES_PER_BLOCK + widx;
    const int tokBase = gw * TOK_PER_WAVE;
    const float4* h4  = (const float4*)h;
    float ps_acc = 0.f;

    float4 hA0[4], hA1[4], hB0[4], hB1[4];
    load_pair(h4, (size_t)tokBase, lane, hA0, hA1);

    #pragma unroll
    for (int bb = 0; bb < TOK_PER_WAVE / 4; ++bb) {
        const int tA = tokBase + 4 * bb;
        const int tB = tA + 2;
        load_pair(h4, (size_t)tB, lane, hB0, hB1);                 // prefetch B
        process_pair(hA0, hA1, Wf, lane, tA, out_w, out_sel, ps_acc, s_cnt);
        if (bb < TOK_PER_WAVE / 4 - 1)
            load_pair(h4, (size_t)(tA + 4), lane, hA0, hA1);       // prefetch next A
        process_pair(hB0, hB1, Wf, lane, tB, out_w, out_sel, ps_acc, s_cnt);
    }

    if (lane < 16) atomicAdd(&s_ps[lane & 7], ps_acc);
    __syncthreads();

    // Banked device-scope accumulation: 32 adds per address total.
    const int bank = blockIdx.x & (NBANK - 1);
    if (tid < 8) {
        atomicAdd(&g_bank[bank * 16 + tid],     s_ps[tid]);
        atomicAdd(&g_bank[bank * 16 + 8 + tid], (float)s_cnt[tid]);  // int sums <2^24: exact
    }
    // __syncthreads drains each wave's outstanding vmem (compiler emits
    // s_waitcnt vmcnt(0) before s_barrier) -> all 16 adds complete before
    // the ticket bump. No threadfence needed: atomics are device-coherent.
    __syncthreads();
    __shared__ unsigned s_old;
    if (tid == 0) s_old = atomicAdd(g_ctr, 1u);
    __syncthreads();

    if (s_old == NBLOCKS - 1) {
        // Last block: read banks via device-scope atomic reads (no stale-L2
        // path), reduce, write aux. 512 independent reads, pipelined.
        __shared__ float s_fin[16];
        if (tid < 16) {
            float v = 0.f;
            #pragma unroll
            for (int b = 0; b < NBANK; ++b)
                v += atomicAdd(&g_bank[b * 16 + tid], 0.0f);
            s_fin[tid] = v;
        }
        __syncthreads();
        if (tid == 0) {
            const float invT = 1.0f / (float)NTOK;
            float a = 0.f;
            #pragma unroll
            for (int e = 0; e < 8; ++e)
                a += (s_fin[8 + e] * invT) * (s_fin[e] * invT);
            *aux = (float)NEXP * a;
        }
    }
}

extern "C" void kernel_launch(void* const* d_in, const int* in_sizes, int n_in,
                              void* d_out, int out_size, void* d_ws, size_t ws_size,
                              hipStream_t stream) {
    const float* h  = (const float*)d_in[0];   // [4, 8192, 1024] f32
    const float* wg = (const float*)d_in[1];   // [8, 1024] f32

    float* out_w   = (float*)d_out;            // [4,8192,2,1] -> 65536
    float* out_sel = out_w + 65536;            // [4,8192,2]   -> 65536 (as float)
    float* aux     = out_w + 131072;           // scalar

    float*    g_bank = (float*)d_ws;                   // 32 banks x 16 floats
    unsigned* g_ctr  = (unsigned*)(g_bank + NBANK*16); // ticket counter

    hipMemsetAsync(d_ws, 0, (NBANK * 16 + 1) * sizeof(float), stream);
    moe_router_kernel<<<NBLOCKS, 256, 0, stream>>>(h, wg, out_w, out_sel, aux,
                                                   g_bank, g_ctr);
}

// Round 9
// 32.184 us; speedup vs baseline: 3.8080x; 1.3241x over previous
//
#include <hip/hip_runtime.h>

#define HIDDEN   1024
#define NEXP     8
#define NTOK     32768           // 4 * 8192
#define TOK_PER_WAVE 8
#define WAVES_PER_BLOCK 4
#define NBLOCKS  (NTOK / (TOK_PER_WAVE * WAVES_PER_BLOCK))   // 1024

// Dual-token 64-lane reduction, stage-interleaved (ILP 2 on DS pipe).
// Per-token op sequence bitwise identical to proven rounds 1-8.
__device__ __forceinline__ void split_reduce8x2(const float (&A)[8], const float (&B)[8],
                                                int lane, float& rA, float& rB) {
    float a4A[4], a4B[4];
    {
        const bool hi = (lane & 4) != 0;
        #pragma unroll
        for (int j = 0; j < 4; ++j) {
            float sA = hi ? A[j] : A[j + 4];
            float sB = hi ? B[j] : B[j + 4];
            float vA = __shfl_xor(sA, 4, 64);
            float vB = __shfl_xor(sB, 4, 64);
            a4A[j] = (hi ? A[j + 4] : A[j]) + vA;
            a4B[j] = (hi ? B[j + 4] : B[j]) + vB;
        }
    }
    float a2A[2], a2B[2];
    {
        const bool hi = (lane & 2) != 0;
        #pragma unroll
        for (int j = 0; j < 2; ++j) {
            float sA = hi ? a4A[j] : a4A[j + 2];
            float sB = hi ? a4B[j] : a4B[j + 2];
            float vA = __shfl_xor(sA, 2, 64);
            float vB = __shfl_xor(sB, 2, 64);
            a2A[j] = (hi ? a4A[j + 2] : a4A[j]) + vA;
            a2B[j] = (hi ? a4B[j + 2] : a4B[j]) + vB;
        }
    }
    float a1A, a1B;
    {
        const bool hi = (lane & 1) != 0;
        float sA = hi ? a2A[0] : a2A[1];
        float sB = hi ? a2B[0] : a2B[1];
        float vA = __shfl_xor(sA, 1, 64);
        float vB = __shfl_xor(sB, 1, 64);
        a1A = (hi ? a2A[1] : a2A[0]) + vA;
        a1B = (hi ? a2B[1] : a2B[0]) + vB;
    }
    {
        float vA = __shfl_xor(a1A, 8, 64);
        float vB = __shfl_xor(a1B, 8, 64);
        a1A += vA; a1B += vB;
        vA = __shfl_xor(a1A, 16, 64);
        vB = __shfl_xor(a1B, 16, 64);
        a1A += vA; a1B += vB;
        vA = __shfl_xor(a1A, 32, 64);
        vB = __shfl_xor(a1B, 32, 64);
        a1A += vA; a1B += vB;
    }
    rA = a1A; rB = a1B;
}

// Per-lane-group softmax+top2 (unchanged, proven rounds 2-8).
__device__ __forceinline__ void softmax_top2_lane(float selv, int lane,
                                                  float& w1, float& w2,
                                                  int& i1, int& i2, float& myp) {
    const int gbase = lane & 56;
    float l[8];
    #pragma unroll
    for (int e = 0; e < 8; ++e) l[e] = __shfl(selv, gbase + e, 64);
    float m = l[0];
    #pragma unroll
    for (int e = 1; e < 8; ++e) m = fmaxf(m, l[e]);
    float p[8];
    float s = 0.f;
    #pragma unroll
    for (int e = 0; e < 8; ++e) { p[e] = __expf(l[e] - m); s += p[e]; }
    const float inv = 1.f / s;

    i1 = 0; float v1 = p[0];
    #pragma unroll
    for (int e = 1; e < 8; ++e) { if (p[e] > v1) { v1 = p[e]; i1 = e; } }
    i2 = -1; float v2 = -1.f;
    #pragma unroll
    for (int e = 0; e < 8; ++e) { if (e != i1 && p[e] > v2) { v2 = p[e]; i2 = e; } }

    const float wsum = v1 + v2;
    w1 = v1 / wsum;
    w2 = v2 / wsum;
    myp = p[lane & 7] * inv;
}

__device__ __forceinline__ void load_pair(const float4* __restrict__ h4,
                                          size_t tok, int lane,
                                          float4 (&h0)[4], float4 (&h1)[4]) {
    const size_t base = tok * 256;   // 256 float4 per row
    #pragma unroll
    for (int j = 0; j < 4; ++j) h0[j] = h4[base + j * 64 + lane];
    #pragma unroll
    for (int j = 0; j < 4; ++j) h1[j] = h4[base + 256 + j * 64 + lane];
}

// W now read from LDS (s_w), 4 x ds_read_b128 per expert per pair.
// Same element mapping as the global-load version -> bit-identical FMAs.
__device__ __forceinline__ void process_pair(const float4 (&h0)[4], const float4 (&h1)[4],
                                             const float4* __restrict__ s_w,
                                             int lane, int t0,
                                             float* __restrict__ out_w,
                                             float* __restrict__ out_sel,
                                             float& ps_acc, unsigned* s_cnt) {
    float acc0[8], acc1[8];
    #pragma unroll
    for (int e = 0; e < 8; ++e) {
        float4 Wf[4];
        #pragma unroll
        for (int j = 0; j < 4; ++j) Wf[j] = s_w[e * 256 + j * 64 + lane];
        float a = 0.f, c = 0.f;
        #pragma unroll
        for (int j = 0; j < 4; ++j) {
            a = fmaf(h0[j].x, Wf[j].x, a);
            a = fmaf(h0[j].y, Wf[j].y, a);
            a = fmaf(h0[j].z, Wf[j].z, a);
            a = fmaf(h0[j].w, Wf[j].w, a);
            c = fmaf(h1[j].x, Wf[j].x, c);
            c = fmaf(h1[j].y, Wf[j].y, c);
            c = fmaf(h1[j].z, Wf[j].z, c);
            c = fmaf(h1[j].w, Wf[j].w, c);
        }
        acc0[e] = a; acc1[e] = c;
    }

    float r0, r1;
    split_reduce8x2(acc0, acc1, lane, r0, r1);

    const int tokSel = (lane >> 3) & 1;      // 8-lane groups alternate tokens
    const float selv = tokSel ? r1 : r0;

    float w1, w2, myp; int i1, i2;
    softmax_top2_lane(selv, lane, w1, w2, i1, i2, myp);

    // lanes 0-15 own aux prob accumulation (expert lane&7, token lane>>3)
    ps_acc += myp;

    // expert-count: lanes 0,1 (token0 i1,i2) and 8,9 (token1 i1,i2)
    if ((lane & 54) == 0)
        atomicAdd(&s_cnt[(lane & 1) ? i2 : i1], 1u);

    // writes: lane 0 -> token t0, lane 8 -> token t0+1
    if ((lane & 55) == 0) {
        const int t = t0 + tokSel;
        ((float2*)out_w)[t]   = make_float2(w1, w2);
        ((float2*)out_sel)[t] = make_float2((float)i1, (float)i2);
    }
}

// launch_bounds: max-threads only (round 3: min-waves=4 forced 64-VGPR
// target -> 122 MB spill, 3.5x regression).
// W_gate staged in LDS: rounds 2-8 all showed VGPR~108-128 < the 128-float
// W tile, i.e. the compiler rematerialized 32 W global-loads per pair
// (40 loads/pair instead of 8; ~2 MB/CU of L1 re-reads). LDS puts W on
// the 256 B/cy DS pipe and makes the global stream pure-h.
__global__ __launch_bounds__(256)
void moe_router_kernel(const float* __restrict__ h, const float* __restrict__ wg,
                       float* __restrict__ out_w, float* __restrict__ out_sel,
                       float* __restrict__ ws) {
    __shared__ float4   s_w[2048];     // 32 KB: full W_gate [8][1024] f32
    __shared__ float    s_ps[8];
    __shared__ unsigned s_cnt[8];
    const int tid  = threadIdx.x;
    const int lane = tid & 63;
    const int widx = tid >> 6;

    if (tid < 8) { s_ps[tid] = 0.f; s_cnt[tid] = 0u; }
    {
        const float4* wg4 = (const float4*)wg;
        #pragma unroll
        for (int i = 0; i < 8; ++i)
            s_w[tid + i * 256] = wg4[tid + i * 256];
    }
    __syncthreads();

    const int gw      = blockIdx.x * WAVES_PER_BLOCK + widx;
    const int tokBase = gw * TOK_PER_WAVE;
    const float4* h4  = (const float4*)h;
    float ps_acc = 0.f;

    float4 hA0[4], hA1[4], hB0[4], hB1[4];
    load_pair(h4, (size_t)tokBase, lane, hA0, hA1);

    #pragma unroll
    for (int bb = 0; bb < TOK_PER_WAVE / 4; ++bb) {
        const int tA = tokBase + 4 * bb;
        const int tB = tA + 2;
        load_pair(h4, (size_t)tB, lane, hB0, hB1);                 // prefetch B
        process_pair(hA0, hA1, s_w, lane, tA, out_w, out_sel, ps_acc, s_cnt);
        if (bb < TOK_PER_WAVE / 4 - 1)
            load_pair(h4, (size_t)(tA + 4), lane, hA0, hA1);       // prefetch next A
        process_pair(hB0, hB1, s_w, lane, tB, out_w, out_sel, ps_acc, s_cnt);
    }

    if (lane < 16) atomicAdd(&s_ps[lane & 7], ps_acc);
    __syncthreads();

    // ws layout: [16][NBLOCKS] so finalize reads coalesced float4.
    if (tid < 8) {
        ws[(size_t)tid * NBLOCKS + blockIdx.x]       = s_ps[tid];
        ws[(size_t)(tid + 8) * NBLOCKS + blockIdx.x] = (float)s_cnt[tid];  // exact (<=64)
    }
}

__global__ void moe_finalize_kernel(const float* __restrict__ ws,
                                    float* __restrict__ aux_out) {
    __shared__ float s[256];
    const int t = threadIdx.x;
    const int k = t >> 4;         // 0-7: ps_e, 8-15: cnt_e
    const int j = t & 15;         // 16 threads per k
    const float4* w4 = (const float4*)(ws + (size_t)k * NBLOCKS);  // 256 float4 per k
    float acc = 0.f;
    #pragma unroll
    for (int i = 0; i < 16; ++i) {
        float4 v = w4[j + i * 16];
        acc += v.x + v.y + v.z + v.w;
    }
    s[t] = acc;
    __syncthreads();
    if (t < 16) {
        float v = 0.f;
        #pragma unroll
        for (int c = 0; c < 16; ++c) v += s[t * 16 + c];
        s[t] = v;
    }
    __syncthreads();
    if (t == 0) {
        const float invT = 1.0f / (float)NTOK;
        float a = 0.f;
        #pragma unroll
        for (int e = 0; e < 8; ++e)
            a += (s[8 + e] * invT) * (s[e] * invT);
        *aux_out = (float)NEXP * a;
    }
}

extern "C" void kernel_launch(void* const* d_in, const int* in_sizes, int n_in,
                              void* d_out, int out_size, void* d_ws, size_t ws_size,
                              hipStream_t stream) {
    const float* h  = (const float*)d_in[0];   // [4, 8192, 1024] f32
    const float* wg = (const float*)d_in[1];   // [8, 1024] f32

    float* out_w   = (float*)d_out;            // [4,8192,2,1] -> 65536
    float* out_sel = out_w + 65536;            // [4,8192,2]   -> 65536 (as float)
    float* aux     = out_w + 131072;           // scalar

    float* ws = (float*)d_ws;                  // [16][1024] floats (fully rewritten every call)

    moe_router_kernel<<<NBLOCKS, 256, 0, stream>>>(h, wg, out_w, out_sel, ws);
    moe_finalize_kernel<<<1, 256, 0, stream>>>(ws, aux);
}